// Round 6
// baseline (594.992 us; speedup 1.0000x reference)
//
#include <hip/hip_runtime.h>

// GNN: 3x (GCNConv -> BN -> ReLU) -> mean/max pool per graph -> 3-layer MLP.
// N=50000 nodes, E=800000 edges, F=H=128, G=1024 graphs.
// conv bias cancels inside BatchNorm (mean-subtraction) -> skipped entirely.
// CSR built with dense writes: bucket(64 nodes) scatter via 782 frontier
// cursors -> per-bucket in-LDS fine sort (no random 4B line-evict scatter).
// H2 and B activations stored bf16 (BN is self-consistent on bf16 values).
// GEMM: MFMA 16x16x32 bf16, no LDS; W pre-packed into fragment order.
// BN-apply+ReLU folded into the NEXT consumer (GEMM staging / pooling).
// Pooling uses sorted `batch` (binary-searched boundaries) -> no atomics.

constexpr int FH = 128;     // feature dim
constexpr int GG = 1024;    // graphs
constexpr int NSB = 256;    // stats partial blocks
constexpr float EPSV = 1e-5f;

typedef __attribute__((ext_vector_type(8))) short short8v;   // 8 bf16 (4 VGPRs)
typedef __attribute__((ext_vector_type(4))) float f32x4;     // MFMA acc

__device__ inline unsigned short bf16_rn(float x) {
    unsigned u = __float_as_uint(x);
    unsigned r = (u + 0x7FFFu + ((u >> 16) & 1u)) >> 16;
    return (unsigned short)r;
}
__device__ inline float bflo(unsigned u) { return __uint_as_float(u << 16); }
__device__ inline float bfhi(unsigned u) { return __uint_as_float(u & 0xFFFF0000u); }
__device__ inline float4 bf4tof(ushort4 h) {
    return make_float4(__uint_as_float((unsigned)h.x << 16),
                       __uint_as_float((unsigned)h.y << 16),
                       __uint_as_float((unsigned)h.z << 16),
                       __uint_as_float((unsigned)h.w << 16));
}

// ---------------- degree ----------------
__global__ void k_deg(const int* __restrict__ dst, unsigned* __restrict__ deg, int E) {
    int e = blockIdx.x * 256 + threadIdx.x;
    if (e < E) atomicAdd(&deg[dst[e]], 1u);
}

__global__ void k_dinv(const unsigned* __restrict__ deg, float* __restrict__ dinv, int n) {
    int i = blockIdx.x * 256 + threadIdx.x;
    if (i < n) dinv[i] = rsqrtf((float)deg[i] + 1.0f);  // +1 = self loop
}

// ---------------- hierarchical exclusive scan of deg -> rowptr ----------------
__global__ __launch_bounds__(1024) void k_scan1(const unsigned* __restrict__ deg,
                                                int* __restrict__ rowptr, int* __restrict__ bsum, int n) {
    __shared__ int wsum[16];
    int i = blockIdx.x * 1024 + threadIdx.x;
    int lane = threadIdx.x & 63, wid = threadIdx.x >> 6;
    int v = (i < n) ? (int)deg[i] : 0;
    int incl = v;
    #pragma unroll
    for (int off = 1; off < 64; off <<= 1) {
        int t = __shfl_up(incl, off, 64);
        if (lane >= off) incl += t;
    }
    if (lane == 63) wsum[wid] = incl;
    __syncthreads();
    int woff = 0;
    #pragma unroll
    for (int w = 0; w < 16; ++w) woff += (w < wid) ? wsum[w] : 0;
    if (i < n) rowptr[i] = woff + incl - v;          // block-local exclusive
    if (threadIdx.x == 1023) bsum[blockIdx.x] = woff + incl;  // block total
}

__global__ void k_scan2(int* __restrict__ bsum, int* __restrict__ rowptr_n, int nb) {
    int lane = threadIdx.x;   // 64 threads, nb <= 64
    int v = (lane < nb) ? bsum[lane] : 0;
    int incl = v;
    #pragma unroll
    for (int off = 1; off < 64; off <<= 1) {
        int t = __shfl_up(incl, off, 64);
        if (lane >= off) incl += t;
    }
    if (lane < nb) bsum[lane] = incl - v;            // exclusive block offsets
    if (lane == 63) *rowptr_n = incl;                // grand total
}

__global__ __launch_bounds__(1024) void k_scan3(int* __restrict__ rowptr,
                                                const int* __restrict__ bsum, int n) {
    int i = blockIdx.x * 1024 + threadIdx.x;
    if (i < n) rowptr[i] += bsum[blockIdx.x];
}

// ---------------- bucket cursors: bcur[k] = rowptr[k*64] ----------------
__global__ void k_bcur(const int* __restrict__ rowptr, int* __restrict__ bcur, int nbk) {
    int k = blockIdx.x * 256 + threadIdx.x;
    if (k < nbk) bcur[k] = rowptr[k << 6];
}

// ---------------- phase C: scatter edges to bucket-grouped tmp (dense frontiers) ----------------
__global__ void k_binscatter(const int* __restrict__ src, const int* __restrict__ dst,
                             int* __restrict__ bcur, uint2* __restrict__ tmp, int E) {
    int e = blockIdx.x * 256 + threadIdx.x;
    if (e < E) {
        int s = src[e], d = dst[e];
        int p = atomicAdd(&bcur[d >> 6], 1);
        tmp[p] = make_uint2((unsigned)s, (unsigned)d);
    }
}

// ---------------- phase D: per-bucket fine sort into final CSR (block-owned dense region) ----------------
__global__ __launch_bounds__(256) void k_finesort(const uint2* __restrict__ tmp,
                                                  const int* __restrict__ rowptr,
                                                  int* __restrict__ csr_src, int n) {
    __shared__ int cur[64];
    int nb0 = blockIdx.x << 6;
    int tid = threadIdx.x;
    int hi = min(nb0 + 64, n);
    if (tid < 64 && nb0 + tid < n) cur[tid] = rowptr[nb0 + tid];
    __syncthreads();
    int estart = rowptr[nb0], eend = rowptr[hi];
    for (int e = estart + tid; e < eend; e += 256) {
        uint2 pr = tmp[e];
        int p = atomicAdd(&cur[pr.y & 63], 1);
        csr_src[p] = (int)pr.x;
    }
}

// ---------------- graph boundaries from sorted batch ----------------
__global__ void k_gptr(const int* __restrict__ batch, int* __restrict__ gptr, int n) {
    int g = blockIdx.x * 256 + threadIdx.x;
    if (g > GG) return;
    int lo = 0, hi = n;                       // first index with batch[i] >= g
    while (lo < hi) { int mid = (lo + hi) >> 1; if (batch[mid] < g) lo = mid + 1; else hi = mid; }
    gptr[g] = lo;
}

// ---------------- W prep: pack 3 layers of W into MFMA B-fragment order ----------------
// lane L's B-frag (nt,kb) = short8 at Wt_l + (nt*4+kb)*512 + L*8  (coalesced).
__global__ void k_wprep(const float* __restrict__ W0, const float* __restrict__ W12,
                        unsigned short* __restrict__ Wt) {
    int t = blockIdx.x * 256 + threadIdx.x;          // 0 .. 3*16384-1
    int l = t >> 14, o = t & 16383;
    const float* W = (l == 0) ? W0 : W12 + (size_t)(l - 1) * 16384;
    int j = o & 7, c = (o >> 3) & 15, hi = (o >> 7) & 3, kb = (o >> 9) & 3, nt = o >> 11;
    int k = kb * 32 + hi * 8 + j;
    int col = nt * 16 + c;
    Wt[t] = bf16_rn(W[k * 128 + col]);
}

// ---------------- GEMM: H2 = bf16( (bn_relu(X) @ W) * dinv[row] ), MFMA ----------------
// block = 256 threads = 4 waves; wave w owns rows [blk*64 + w*16, +16), all 128 cols.
// BF16IN: X is bf16 with BN scale/shift+ReLU applied on the fly (layers 1,2).
// !BF16IN: X is raw f32 input (layer 0, no BN).
template<bool BF16IN>
__global__ __launch_bounds__(256) void k_gemm(const void* __restrict__ Xp,
                                              const unsigned short* __restrict__ Wt,
                                              const float* __restrict__ dinv,
                                              const float* __restrict__ sc,
                                              const float* __restrict__ sh,
                                              unsigned short* __restrict__ H, int n) {
    int wave = threadIdx.x >> 6, L = threadIdx.x & 63;
    int hi = L >> 4, c16 = L & 15;
    int m0 = blockIdx.x * 64 + wave * 16;
    int arow = m0 + c16;                   // A-frag row this lane loads
    bool okA = arow < n;

    short8v aF[4];
    #pragma unroll
    for (int kb = 0; kb < 4; ++kb) {
        int kc = kb * 32 + hi * 8;
        float v[8];
        #pragma unroll
        for (int j = 0; j < 8; ++j) v[j] = 0.f;
        if (okA) {
            if constexpr (BF16IN) {
                const unsigned short* Xb = (const unsigned short*)Xp;
                uint4 raw = *(const uint4*)&Xb[(size_t)arow * 128 + kc];
                v[0] = bflo(raw.x); v[1] = bfhi(raw.x);
                v[2] = bflo(raw.y); v[3] = bfhi(raw.y);
                v[4] = bflo(raw.z); v[5] = bfhi(raw.z);
                v[6] = bflo(raw.w); v[7] = bfhi(raw.w);
                float4 s0 = *(const float4*)&sc[kc], s1 = *(const float4*)&sc[kc + 4];
                float4 h0 = *(const float4*)&sh[kc], h1 = *(const float4*)&sh[kc + 4];
                v[0] = fmaxf(fmaf(v[0], s0.x, h0.x), 0.f);
                v[1] = fmaxf(fmaf(v[1], s0.y, h0.y), 0.f);
                v[2] = fmaxf(fmaf(v[2], s0.z, h0.z), 0.f);
                v[3] = fmaxf(fmaf(v[3], s0.w, h0.w), 0.f);
                v[4] = fmaxf(fmaf(v[4], s1.x, h1.x), 0.f);
                v[5] = fmaxf(fmaf(v[5], s1.y, h1.y), 0.f);
                v[6] = fmaxf(fmaf(v[6], s1.z, h1.z), 0.f);
                v[7] = fmaxf(fmaf(v[7], s1.w, h1.w), 0.f);
            } else {
                const float* Xf = (const float*)Xp;
                float4 v0 = *(const float4*)&Xf[(size_t)arow * 128 + kc];
                float4 v1 = *(const float4*)&Xf[(size_t)arow * 128 + kc + 4];
                v[0] = v0.x; v[1] = v0.y; v[2] = v0.z; v[3] = v0.w;
                v[4] = v1.x; v[5] = v1.y; v[6] = v1.z; v[7] = v1.w;
            }
        }
        short8v a;
        #pragma unroll
        for (int j = 0; j < 8; ++j) a[j] = (short)bf16_rn(v[j]);
        aF[kb] = a;
    }

    f32x4 acc[8];
    #pragma unroll
    for (int nt = 0; nt < 8; ++nt) {
        acc[nt][0] = 0.f; acc[nt][1] = 0.f; acc[nt][2] = 0.f; acc[nt][3] = 0.f;
    }
    #pragma unroll
    for (int nt = 0; nt < 8; ++nt) {
        #pragma unroll
        for (int kb = 0; kb < 4; ++kb) {
            short8v bF = *(const short8v*)&Wt[(size_t)(nt * 4 + kb) * 512 + L * 8];
            acc[nt] = __builtin_amdgcn_mfma_f32_16x16x32_bf16(aF[kb], bF, acc[nt], 0, 0, 0);
        }
    }

    // epilogue: C row = m0 + hi*4 + reg, col = nt*16 + c16
    #pragma unroll
    for (int reg = 0; reg < 4; ++reg) {
        int row = m0 + hi * 4 + reg;
        if (row < n) {
            float dv = dinv[row];
            #pragma unroll
            for (int nt = 0; nt < 8; ++nt)
                H[(size_t)row * 128 + nt * 16 + c16] = bf16_rn(acc[nt][reg] * dv);
        }
    }
}

// ---------------- pull aggregation: B[d] = bf16( dinv[d] * (H2[d] + sum H2[src]) ) ----------------
__global__ __launch_bounds__(256) void k_aggregate(const int* __restrict__ rowptr, const int* __restrict__ csr_src,
                                                   const float* __restrict__ dinv,
                                                   const unsigned short* __restrict__ H2,
                                                   unsigned short* __restrict__ Bo, int n) {
    int node = blockIdx.x * 8 + (threadIdx.x >> 5);
    if (node >= n) return;
    int lane = threadIdx.x & 31;
    int beg = rowptr[node], end = rowptr[node + 1];
    float dv = dinv[node];
    const ushort4* Hv = (const ushort4*)H2;              // row = 32 ushort4
    float4 acc = bf4tof(Hv[(size_t)node * 32 + lane]);   // self loop
    float4 acc2 = make_float4(0.f, 0.f, 0.f, 0.f);
    int e = beg;
    for (; e + 1 < end; e += 2) {
        int s0 = csr_src[e], s1 = csr_src[e + 1];
        float4 h0 = bf4tof(Hv[(size_t)s0 * 32 + lane]);
        float4 h1 = bf4tof(Hv[(size_t)s1 * 32 + lane]);
        acc.x += h0.x;  acc.y += h0.y;  acc.z += h0.z;  acc.w += h0.w;
        acc2.x += h1.x; acc2.y += h1.y; acc2.z += h1.z; acc2.w += h1.w;
    }
    if (e < end) {
        int s0 = csr_src[e];
        float4 h0 = bf4tof(Hv[(size_t)s0 * 32 + lane]);
        acc.x += h0.x; acc.y += h0.y; acc.z += h0.z; acc.w += h0.w;
    }
    ushort4 o;
    o.x = bf16_rn((acc.x + acc2.x) * dv);
    o.y = bf16_rn((acc.y + acc2.y) * dv);
    o.z = bf16_rn((acc.z + acc2.z) * dv);
    o.w = bf16_rn((acc.w + acc2.w) * dv);
    *(ushort4*)&Bo[(size_t)node * 128 + lane * 4] = o;
}

// ---------------- BN stats over bf16 B: per-block partial sum & sumsq ----------------
__global__ __launch_bounds__(256) void k_stats(const unsigned short* __restrict__ X,
                                               float* __restrict__ partials, int n) {
    __shared__ float sb[4][128];
    int tid = threadIdx.x;
    int fp = tid & 63, sub = tid >> 6;       // feature pair, 4 row sub-streams
    float s0 = 0.f, s1 = 0.f, q0 = 0.f, q1 = 0.f;
    for (int r = blockIdx.x * 4 + sub; r < n; r += NSB * 4) {
        unsigned u = *(const unsigned*)&X[(size_t)r * 128 + fp * 2];
        float v0 = bflo(u), v1 = bfhi(u);
        s0 += v0; q0 = fmaf(v0, v0, q0);
        s1 += v1; q1 = fmaf(v1, v1, q1);
    }
    sb[sub][fp * 2] = s0; sb[sub][fp * 2 + 1] = s1;
    __syncthreads();
    if (tid < 128) partials[(size_t)blockIdx.x * 256 + tid] =
        sb[0][tid] + sb[1][tid] + sb[2][tid] + sb[3][tid];
    __syncthreads();
    sb[sub][fp * 2] = q0; sb[sub][fp * 2 + 1] = q1;
    __syncthreads();
    if (tid < 128) partials[(size_t)blockIdx.x * 256 + 128 + tid] =
        sb[0][tid] + sb[1][tid] + sb[2][tid] + sb[3][tid];
}

// ---------------- finalize stats -> scale/shift ----------------
__global__ __launch_bounds__(128) void k_finstats(const float* __restrict__ partials,
                                                  const float* __restrict__ gamma, const float* __restrict__ beta,
                                                  float* __restrict__ sc, float* __restrict__ sh, int n) {
    int f = threadIdx.x;
    float s = 0.f, q = 0.f;
    for (int b = 0; b < NSB; ++b) {
        s += partials[(size_t)b * 256 + f];
        q += partials[(size_t)b * 256 + 128 + f];
    }
    float invN = 1.0f / (float)n;
    float mu = s * invN;
    float var = fmaf(-mu, mu, q * invN);
    float scale = gamma[f] * rsqrtf(var + EPSV);
    sc[f] = scale;
    sh[f] = fmaf(-mu, scale, beta[f]);
}

// ---------------- pooling over sorted batch: mean & max, fused final BN+ReLU ----------------
__global__ __launch_bounds__(256) void k_pool(const unsigned short* __restrict__ X, const int* __restrict__ gptr,
                                              const float* __restrict__ sc, const float* __restrict__ sh,
                                              float* __restrict__ pooled) {
    __shared__ float shm[256];
    int g = blockIdx.x;
    int t = threadIdx.x;
    int f = t & 127, sub = t >> 7;
    int beg = gptr[g], end = gptr[g + 1];
    float scf = sc[f], shf = sh[f];
    float s = 0.f, m = 0.f;
    for (int r = beg + sub; r < end; r += 2) {
        float xv = __uint_as_float((unsigned)X[(size_t)r * 128 + f] << 16);
        float v = fmaxf(fmaf(xv, scf, shf), 0.f);
        s += v; m = fmaxf(m, v);
    }
    shm[t] = s;
    __syncthreads();
    if (sub == 0) {
        int c = end - beg;
        float inv = (c > 0) ? 1.0f / (float)c : 0.f;
        pooled[(size_t)g * 256 + f] = (s + shm[t + 128]) * inv;
    }
    __syncthreads();
    shm[t] = m;
    __syncthreads();
    if (sub == 1) {
        pooled[(size_t)g * 256 + 128 + f] = fmaxf(m, shm[t - 128]);  // 0 for empty graph = reference
    }
}

// ---------------- MLP ----------------
__global__ __launch_bounds__(256) void k_mlp1(const float* __restrict__ pooled, const float* __restrict__ W1,
                                              const float* __restrict__ b1, float* __restrict__ H1) {
    __shared__ float grow[256];
    int gi = blockIdx.x, t = threadIdx.x;
    grow[t] = pooled[(size_t)gi * 256 + t];
    __syncthreads();
    float acc = b1[t];
    #pragma unroll 8
    for (int k = 0; k < 256; ++k) acc = fmaf(grow[k], W1[k * 256 + t], acc);
    H1[gi * 256 + t] = fmaxf(acc, 0.f);
}

__global__ __launch_bounds__(128) void k_mlp2(const float* __restrict__ H1, const float* __restrict__ W2,
                                              const float* __restrict__ b2, float* __restrict__ H2) {
    __shared__ float row[256];
    int gi = blockIdx.x, t = threadIdx.x;
    row[t] = H1[gi * 256 + t];
    row[t + 128] = H1[gi * 256 + t + 128];
    __syncthreads();
    float acc = b2[t];
    #pragma unroll 8
    for (int k = 0; k < 256; ++k) acc = fmaf(row[k], W2[k * 128 + t], acc);
    H2[gi * 128 + t] = fmaxf(acc, 0.f);
}

__global__ __launch_bounds__(256) void k_mlp3(const float* __restrict__ H2, const float* __restrict__ W3,
                                              const float* __restrict__ b3, float* __restrict__ out) {
    int gi = blockIdx.x * 4 + (threadIdx.x >> 6);
    int lane = threadIdx.x & 63;
    float v = H2[gi * 128 + lane] * W3[lane] + H2[gi * 128 + 64 + lane] * W3[64 + lane];
    #pragma unroll
    for (int off = 32; off; off >>= 1) v += __shfl_down(v, off);
    if (lane == 0) out[gi] = v + b3[0];
}

extern "C" void kernel_launch(void* const* d_in, const int* in_sizes, int n_in,
                              void* d_out, int out_size, void* d_ws, size_t ws_size,
                              hipStream_t stream) {
    const float* x      = (const float*)d_in[0];
    const int*   ei     = (const int*)d_in[1];
    const int*   batch  = (const int*)d_in[2];
    const float* convW0 = (const float*)d_in[3];
    const float* convW  = (const float*)d_in[4];
    // d_in[5] convb: cancels inside BatchNorm, unused
    const float* gamma  = (const float*)d_in[6];
    const float* beta   = (const float*)d_in[7];
    const float* mW1    = (const float*)d_in[8];
    const float* mb1    = (const float*)d_in[9];
    const float* mW2    = (const float*)d_in[10];
    const float* mb2    = (const float*)d_in[11];
    const float* mW3    = (const float*)d_in[12];
    const float* mb3    = (const float*)d_in[13];
    float* out = (float*)d_out;

    const int E = in_sizes[1] / 2;
    const int n = in_sizes[0] / FH;
    const int npad = (n + 4) & ~3;
    const int nb = (n + 1023) / 1024;
    const int nbk = (n + 63) >> 6;            // 64-node buckets

    // workspace layout (16B-aligned chunks)
    float*          A     = (float*)d_ws;                     // n*128 f32 slot: bf16 H2; tmp overlays pre-loop
    unsigned short* H2b   = (unsigned short*)A;
    uint2*          tmp   = (uint2*)A;                        // E uint2 (6.4MB <= 25.6MB slot), pre-loop only
    float*    B       = A + (size_t)n * FH;                   // n*128 f32 slot: bf16 B; bcur overlays pre-loop
    unsigned short* Bb = (unsigned short*)B;
    int*      bcur    = (int*)B;                              // nbk ints, pre-loop only
    float*    dinv    = B + (size_t)n * FH;                   // n
    unsigned* deg     = (unsigned*)(dinv + n);                // n
    float*    parts   = (float*)(deg + n);                    // NSB*256
    float*    sc      = parts + (size_t)NSB * 256;            // 128
    float*    sh      = sc + 128;                             // 128
    float*    pooled  = sh + 128;                             // G*256
    float*    h1      = pooled + (size_t)GG * 256;            // G*256
    float*    h2      = h1 + (size_t)GG * 256;                // G*128
    int*      gptr    = (int*)(h2 + (size_t)GG * FH);         // G+1 (pad 4)
    int*      rowptr  = gptr + ((GG + 4) & ~3);               // n+1 (padded)
    int*      bsum    = rowptr + npad;                        // 64
    int*      csrsrc  = bsum + 64;                            // E
    unsigned short* Wt = (unsigned short*)(csrsrc + ((E + 3) & ~3));  // 3*16384 ushorts

    const int* srcI = ei;
    const int* dstI = ei + E;

    // ---- CSR build (dense writes) + graph boundaries + W prep ----
    hipMemsetAsync(deg, 0, (size_t)n * sizeof(unsigned), stream);
    k_deg<<<(E + 255) / 256, 256, 0, stream>>>(dstI, deg, E);
    k_dinv<<<(n + 255) / 256, 256, 0, stream>>>(deg, dinv, n);
    k_scan1<<<nb, 1024, 0, stream>>>(deg, rowptr, bsum, n);
    k_scan2<<<1, 64, 0, stream>>>(bsum, rowptr + n, nb);
    k_scan3<<<nb, 1024, 0, stream>>>(rowptr, bsum, n);
    k_bcur<<<(nbk + 255) / 256, 256, 0, stream>>>(rowptr, bcur, nbk);
    k_binscatter<<<(E + 255) / 256, 256, 0, stream>>>(srcI, dstI, bcur, tmp, E);
    k_finesort<<<nbk, 256, 0, stream>>>(tmp, rowptr, csrsrc, n);
    k_gptr<<<(GG + 1 + 255) / 256, 256, 0, stream>>>(batch, gptr, n);
    k_wprep<<<3 * 16384 / 256, 256, 0, stream>>>(convW0, convW, Wt);

    for (int l = 0; l < 3; ++l) {
        if (l == 0)
            k_gemm<false><<<(n + 63) / 64, 256, 0, stream>>>(x, Wt, dinv, nullptr, nullptr, H2b, n);
        else
            k_gemm<true><<<(n + 63) / 64, 256, 0, stream>>>(Bb, Wt + (size_t)l * 16384, dinv, sc, sh, H2b, n);
        k_aggregate<<<(n + 7) / 8, 256, 0, stream>>>(rowptr, csrsrc, dinv, H2b, Bb, n);
        k_stats<<<NSB, 256, 0, stream>>>(Bb, parts, n);
        k_finstats<<<1, 128, 0, stream>>>(parts, gamma + l * FH, beta + l * FH, sc, sh, n);
    }

    // pooling (applies layer-3 BN+ReLU on the fly), then MLP
    k_pool<<<GG, 256, 0, stream>>>(Bb, gptr, sc, sh, pooled);
    k_mlp1<<<GG, 256, 0, stream>>>(pooled, mW1, mb1, h1);
    k_mlp2<<<GG, 128, 0, stream>>>(h1, mW2, mb2, h2);
    k_mlp3<<<GG / 4, 256, 0, stream>>>(h2, mW3, mb3, out);
}

// Round 7
// 421.761 us; speedup vs baseline: 1.4107x; 1.4107x over previous
//
#include <hip/hip_runtime.h>

// GNN: 3x (GCNConv -> BN -> ReLU) -> mean/max pool per graph -> 3-layer MLP.
// N=50000 nodes, E=800000 edges, F=H=128, G=1024 graphs.
// conv bias cancels inside BatchNorm (mean-subtraction) -> skipped entirely.
// CSR build: block-level LDS histogram + one line-padded global cursor
// reservation per (block,bucket) -> dense tmp scatter -> per-bucket LDS fine
// sort. No deep same-line atomic serialization anywhere.
// H2 and B activations stored bf16 (BN is self-consistent on bf16 values).
// GEMM: MFMA 16x16x32 bf16, no LDS; W pre-packed into fragment order.
// BN-apply+ReLU folded into the NEXT consumer (GEMM staging / pooling).
// Pooling uses sorted `batch` (binary-searched boundaries) -> no atomics.

constexpr int FH = 128;     // feature dim
constexpr int GG = 1024;    // graphs
constexpr int NSB = 256;    // stats partial blocks
constexpr int BKS = 1024;   // max 64-node buckets supported in LDS (n <= 65536)
constexpr int CPAD = 16;    // global cursor padding in ints = one 64B line
constexpr int EPB = 4096;   // edges per partition block
constexpr float EPSV = 1e-5f;

typedef __attribute__((ext_vector_type(8))) short short8v;   // 8 bf16 (4 VGPRs)
typedef __attribute__((ext_vector_type(4))) float f32x4;     // MFMA acc

__device__ inline unsigned short bf16_rn(float x) {
    unsigned u = __float_as_uint(x);
    unsigned r = (u + 0x7FFFu + ((u >> 16) & 1u)) >> 16;
    return (unsigned short)r;
}
__device__ inline float bflo(unsigned u) { return __uint_as_float(u << 16); }
__device__ inline float bfhi(unsigned u) { return __uint_as_float(u & 0xFFFF0000u); }
__device__ inline float4 bf4tof(ushort4 h) {
    return make_float4(__uint_as_float((unsigned)h.x << 16),
                       __uint_as_float((unsigned)h.y << 16),
                       __uint_as_float((unsigned)h.z << 16),
                       __uint_as_float((unsigned)h.w << 16));
}

// ---------------- degree ----------------
__global__ void k_deg(const int* __restrict__ dst, unsigned* __restrict__ deg, int E) {
    int e = blockIdx.x * 256 + threadIdx.x;
    if (e < E) atomicAdd(&deg[dst[e]], 1u);
}

__global__ void k_dinv(const unsigned* __restrict__ deg, float* __restrict__ dinv, int n) {
    int i = blockIdx.x * 256 + threadIdx.x;
    if (i < n) dinv[i] = rsqrtf((float)deg[i] + 1.0f);  // +1 = self loop
}

// ---------------- hierarchical exclusive scan of deg -> rowptr ----------------
__global__ __launch_bounds__(1024) void k_scan1(const unsigned* __restrict__ deg,
                                                int* __restrict__ rowptr, int* __restrict__ bsum, int n) {
    __shared__ int wsum[16];
    int i = blockIdx.x * 1024 + threadIdx.x;
    int lane = threadIdx.x & 63, wid = threadIdx.x >> 6;
    int v = (i < n) ? (int)deg[i] : 0;
    int incl = v;
    #pragma unroll
    for (int off = 1; off < 64; off <<= 1) {
        int t = __shfl_up(incl, off, 64);
        if (lane >= off) incl += t;
    }
    if (lane == 63) wsum[wid] = incl;
    __syncthreads();
    int woff = 0;
    #pragma unroll
    for (int w = 0; w < 16; ++w) woff += (w < wid) ? wsum[w] : 0;
    if (i < n) rowptr[i] = woff + incl - v;          // block-local exclusive
    if (threadIdx.x == 1023) bsum[blockIdx.x] = woff + incl;  // block total
}

__global__ void k_scan2(int* __restrict__ bsum, int* __restrict__ rowptr_n, int nb) {
    int lane = threadIdx.x;   // 64 threads, nb <= 64
    int v = (lane < nb) ? bsum[lane] : 0;
    int incl = v;
    #pragma unroll
    for (int off = 1; off < 64; off <<= 1) {
        int t = __shfl_up(incl, off, 64);
        if (lane >= off) incl += t;
    }
    if (lane < nb) bsum[lane] = incl - v;            // exclusive block offsets
    if (lane == 63) *rowptr_n = incl;                // grand total
}

__global__ __launch_bounds__(1024) void k_scan3(int* __restrict__ rowptr,
                                                const int* __restrict__ bsum, int n) {
    int i = blockIdx.x * 1024 + threadIdx.x;
    if (i < n) rowptr[i] += bsum[blockIdx.x];
}

// ---------------- bucket cursors (line-padded): bcur[k*CPAD] = rowptr[k*64] ----------------
__global__ void k_bcur(const int* __restrict__ rowptr, int* __restrict__ bcur, int nbk) {
    int k = blockIdx.x * 256 + threadIdx.x;
    if (k < nbk) bcur[k * CPAD] = rowptr[k << 6];
}

// ---------------- phase C: partition edges into 64-node buckets ----------------
// Block-level LDS histogram -> one padded global atomic per (block,bucket)
// -> LDS-cursor scatter of (src,dst) pairs. Edges held in registers.
__global__ __launch_bounds__(256) void k_binscatter(const int* __restrict__ src, const int* __restrict__ dst,
                                                    int* __restrict__ bcur, uint2* __restrict__ tmp,
                                                    int E, int nbk) {
    __shared__ int hist[BKS];
    int tid = threadIdx.x;
    for (int b = tid; b < nbk; b += 256) hist[b] = 0;
    __syncthreads();
    int e0 = blockIdx.x * EPB;
    int s[16], d[16];
    #pragma unroll
    for (int i = 0; i < 16; ++i) {
        int e = e0 + i * 256 + tid;
        if (e < E) {
            s[i] = src[e]; d[i] = dst[e];
            atomicAdd(&hist[d[i] >> 6], 1);
        } else d[i] = -1;
    }
    __syncthreads();
    for (int b = tid; b < nbk; b += 256) {
        int c = hist[b];
        hist[b] = c ? atomicAdd(&bcur[b * CPAD], c) : 0;   // reserve dense run
    }
    __syncthreads();
    #pragma unroll
    for (int i = 0; i < 16; ++i) {
        if (d[i] >= 0) {
            int p = atomicAdd(&hist[d[i] >> 6], 1);
            tmp[p] = make_uint2((unsigned)s[i], (unsigned)d[i]);
        }
    }
}

// ---------------- phase D: per-bucket fine sort into final CSR (block-owned dense region) ----------------
__global__ __launch_bounds__(256) void k_finesort(const uint2* __restrict__ tmp,
                                                  const int* __restrict__ rowptr,
                                                  int* __restrict__ csr_src, int n) {
    __shared__ int cur[64];
    int nb0 = blockIdx.x << 6;
    int tid = threadIdx.x;
    int hi = min(nb0 + 64, n);
    if (tid < 64 && nb0 + tid < n) cur[tid] = rowptr[nb0 + tid];
    __syncthreads();
    int estart = rowptr[nb0], eend = rowptr[hi];
    for (int e = estart + tid; e < eend; e += 256) {
        uint2 pr = tmp[e];
        int p = atomicAdd(&cur[pr.y & 63], 1);
        csr_src[p] = (int)pr.x;
    }
}

// ---------------- graph boundaries from sorted batch ----------------
__global__ void k_gptr(const int* __restrict__ batch, int* __restrict__ gptr, int n) {
    int g = blockIdx.x * 256 + threadIdx.x;
    if (g > GG) return;
    int lo = 0, hi = n;                       // first index with batch[i] >= g
    while (lo < hi) { int mid = (lo + hi) >> 1; if (batch[mid] < g) lo = mid + 1; else hi = mid; }
    gptr[g] = lo;
}

// ---------------- W prep: pack 3 layers of W into MFMA B-fragment order ----------------
// lane L's B-frag (nt,kb) = short8 at Wt_l + (nt*4+kb)*512 + L*8  (coalesced).
__global__ void k_wprep(const float* __restrict__ W0, const float* __restrict__ W12,
                        unsigned short* __restrict__ Wt) {
    int t = blockIdx.x * 256 + threadIdx.x;          // 0 .. 3*16384-1
    int l = t >> 14, o = t & 16383;
    const float* W = (l == 0) ? W0 : W12 + (size_t)(l - 1) * 16384;
    int j = o & 7, c = (o >> 3) & 15, hi = (o >> 7) & 3, kb = (o >> 9) & 3, nt = o >> 11;
    int k = kb * 32 + hi * 8 + j;
    int col = nt * 16 + c;
    Wt[t] = bf16_rn(W[k * 128 + col]);
}

// ---------------- GEMM: H2 = bf16( (bn_relu(X) @ W) * dinv[row] ), MFMA ----------------
// block = 256 threads = 4 waves; wave w owns rows [blk*64 + w*16, +16), all 128 cols.
template<bool BF16IN>
__global__ __launch_bounds__(256) void k_gemm(const void* __restrict__ Xp,
                                              const unsigned short* __restrict__ Wt,
                                              const float* __restrict__ dinv,
                                              const float* __restrict__ sc,
                                              const float* __restrict__ sh,
                                              unsigned short* __restrict__ H, int n) {
    int wave = threadIdx.x >> 6, L = threadIdx.x & 63;
    int hi = L >> 4, c16 = L & 15;
    int m0 = blockIdx.x * 64 + wave * 16;
    int arow = m0 + c16;                   // A-frag row this lane loads
    bool okA = arow < n;

    short8v aF[4];
    #pragma unroll
    for (int kb = 0; kb < 4; ++kb) {
        int kc = kb * 32 + hi * 8;
        float v[8];
        #pragma unroll
        for (int j = 0; j < 8; ++j) v[j] = 0.f;
        if (okA) {
            if constexpr (BF16IN) {
                const unsigned short* Xb = (const unsigned short*)Xp;
                uint4 raw = *(const uint4*)&Xb[(size_t)arow * 128 + kc];
                v[0] = bflo(raw.x); v[1] = bfhi(raw.x);
                v[2] = bflo(raw.y); v[3] = bfhi(raw.y);
                v[4] = bflo(raw.z); v[5] = bfhi(raw.z);
                v[6] = bflo(raw.w); v[7] = bfhi(raw.w);
                float4 s0 = *(const float4*)&sc[kc], s1 = *(const float4*)&sc[kc + 4];
                float4 h0 = *(const float4*)&sh[kc], h1 = *(const float4*)&sh[kc + 4];
                v[0] = fmaxf(fmaf(v[0], s0.x, h0.x), 0.f);
                v[1] = fmaxf(fmaf(v[1], s0.y, h0.y), 0.f);
                v[2] = fmaxf(fmaf(v[2], s0.z, h0.z), 0.f);
                v[3] = fmaxf(fmaf(v[3], s0.w, h0.w), 0.f);
                v[4] = fmaxf(fmaf(v[4], s1.x, h1.x), 0.f);
                v[5] = fmaxf(fmaf(v[5], s1.y, h1.y), 0.f);
                v[6] = fmaxf(fmaf(v[6], s1.z, h1.z), 0.f);
                v[7] = fmaxf(fmaf(v[7], s1.w, h1.w), 0.f);
            } else {
                const float* Xf = (const float*)Xp;
                float4 v0 = *(const float4*)&Xf[(size_t)arow * 128 + kc];
                float4 v1 = *(const float4*)&Xf[(size_t)arow * 128 + kc + 4];
                v[0] = v0.x; v[1] = v0.y; v[2] = v0.z; v[3] = v0.w;
                v[4] = v1.x; v[5] = v1.y; v[6] = v1.z; v[7] = v1.w;
            }
        }
        short8v a;
        #pragma unroll
        for (int j = 0; j < 8; ++j) a[j] = (short)bf16_rn(v[j]);
        aF[kb] = a;
    }

    f32x4 acc[8];
    #pragma unroll
    for (int nt = 0; nt < 8; ++nt) {
        acc[nt][0] = 0.f; acc[nt][1] = 0.f; acc[nt][2] = 0.f; acc[nt][3] = 0.f;
    }
    #pragma unroll
    for (int nt = 0; nt < 8; ++nt) {
        #pragma unroll
        for (int kb = 0; kb < 4; ++kb) {
            short8v bF = *(const short8v*)&Wt[(size_t)(nt * 4 + kb) * 512 + L * 8];
            acc[nt] = __builtin_amdgcn_mfma_f32_16x16x32_bf16(aF[kb], bF, acc[nt], 0, 0, 0);
        }
    }

    // epilogue: C row = m0 + hi*4 + reg, col = nt*16 + c16
    #pragma unroll
    for (int reg = 0; reg < 4; ++reg) {
        int row = m0 + hi * 4 + reg;
        if (row < n) {
            float dv = dinv[row];
            #pragma unroll
            for (int nt = 0; nt < 8; ++nt)
                H[(size_t)row * 128 + nt * 16 + c16] = bf16_rn(acc[nt][reg] * dv);
        }
    }
}

// ---------------- pull aggregation: B[d] = bf16( dinv[d] * (H2[d] + sum H2[src]) ) ----------------
__global__ __launch_bounds__(256) void k_aggregate(const int* __restrict__ rowptr, const int* __restrict__ csr_src,
                                                   const float* __restrict__ dinv,
                                                   const unsigned short* __restrict__ H2,
                                                   unsigned short* __restrict__ Bo, int n) {
    int node = blockIdx.x * 8 + (threadIdx.x >> 5);
    if (node >= n) return;
    int lane = threadIdx.x & 31;
    int beg = rowptr[node], end = rowptr[node + 1];
    float dv = dinv[node];
    const ushort4* Hv = (const ushort4*)H2;              // row = 32 ushort4
    float4 acc = bf4tof(Hv[(size_t)node * 32 + lane]);   // self loop
    float4 acc2 = make_float4(0.f, 0.f, 0.f, 0.f);
    int e = beg;
    for (; e + 1 < end; e += 2) {
        int s0 = csr_src[e], s1 = csr_src[e + 1];
        float4 h0 = bf4tof(Hv[(size_t)s0 * 32 + lane]);
        float4 h1 = bf4tof(Hv[(size_t)s1 * 32 + lane]);
        acc.x += h0.x;  acc.y += h0.y;  acc.z += h0.z;  acc.w += h0.w;
        acc2.x += h1.x; acc2.y += h1.y; acc2.z += h1.z; acc2.w += h1.w;
    }
    if (e < end) {
        int s0 = csr_src[e];
        float4 h0 = bf4tof(Hv[(size_t)s0 * 32 + lane]);
        acc.x += h0.x; acc.y += h0.y; acc.z += h0.z; acc.w += h0.w;
    }
    ushort4 o;
    o.x = bf16_rn((acc.x + acc2.x) * dv);
    o.y = bf16_rn((acc.y + acc2.y) * dv);
    o.z = bf16_rn((acc.z + acc2.z) * dv);
    o.w = bf16_rn((acc.w + acc2.w) * dv);
    *(ushort4*)&Bo[(size_t)node * 128 + lane * 4] = o;
}

// ---------------- BN stats over bf16 B: per-block partial sum & sumsq ----------------
__global__ __launch_bounds__(256) void k_stats(const unsigned short* __restrict__ X,
                                               float* __restrict__ partials, int n) {
    __shared__ float sb[4][128];
    int tid = threadIdx.x;
    int fp = tid & 63, sub = tid >> 6;       // feature pair, 4 row sub-streams
    float s0 = 0.f, s1 = 0.f, q0 = 0.f, q1 = 0.f;
    for (int r = blockIdx.x * 4 + sub; r < n; r += NSB * 4) {
        unsigned u = *(const unsigned*)&X[(size_t)r * 128 + fp * 2];
        float v0 = bflo(u), v1 = bfhi(u);
        s0 += v0; q0 = fmaf(v0, v0, q0);
        s1 += v1; q1 = fmaf(v1, v1, q1);
    }
    sb[sub][fp * 2] = s0; sb[sub][fp * 2 + 1] = s1;
    __syncthreads();
    if (tid < 128) partials[(size_t)blockIdx.x * 256 + tid] =
        sb[0][tid] + sb[1][tid] + sb[2][tid] + sb[3][tid];
    __syncthreads();
    sb[sub][fp * 2] = q0; sb[sub][fp * 2 + 1] = q1;
    __syncthreads();
    if (tid < 128) partials[(size_t)blockIdx.x * 256 + 128 + tid] =
        sb[0][tid] + sb[1][tid] + sb[2][tid] + sb[3][tid];
}

// ---------------- finalize stats -> scale/shift ----------------
__global__ __launch_bounds__(128) void k_finstats(const float* __restrict__ partials,
                                                  const float* __restrict__ gamma, const float* __restrict__ beta,
                                                  float* __restrict__ sc, float* __restrict__ sh, int n) {
    int f = threadIdx.x;
    float s = 0.f, q = 0.f;
    for (int b = 0; b < NSB; ++b) {
        s += partials[(size_t)b * 256 + f];
        q += partials[(size_t)b * 256 + 128 + f];
    }
    float invN = 1.0f / (float)n;
    float mu = s * invN;
    float var = fmaf(-mu, mu, q * invN);
    float scale = gamma[f] * rsqrtf(var + EPSV);
    sc[f] = scale;
    sh[f] = fmaf(-mu, scale, beta[f]);
}

// ---------------- pooling over sorted batch: mean & max, fused final BN+ReLU ----------------
__global__ __launch_bounds__(256) void k_pool(const unsigned short* __restrict__ X, const int* __restrict__ gptr,
                                              const float* __restrict__ sc, const float* __restrict__ sh,
                                              float* __restrict__ pooled) {
    __shared__ float shm[256];
    int g = blockIdx.x;
    int t = threadIdx.x;
    int f = t & 127, sub = t >> 7;
    int beg = gptr[g], end = gptr[g + 1];
    float scf = sc[f], shf = sh[f];
    float s = 0.f, m = 0.f;
    for (int r = beg + sub; r < end; r += 2) {
        float xv = __uint_as_float((unsigned)X[(size_t)r * 128 + f] << 16);
        float v = fmaxf(fmaf(xv, scf, shf), 0.f);
        s += v; m = fmaxf(m, v);
    }
    shm[t] = s;
    __syncthreads();
    if (sub == 0) {
        int c = end - beg;
        float inv = (c > 0) ? 1.0f / (float)c : 0.f;
        pooled[(size_t)g * 256 + f] = (s + shm[t + 128]) * inv;
    }
    __syncthreads();
    shm[t] = m;
    __syncthreads();
    if (sub == 1) {
        pooled[(size_t)g * 256 + 128 + f] = fmaxf(m, shm[t - 128]);  // 0 for empty graph = reference
    }
}

// ---------------- MLP ----------------
__global__ __launch_bounds__(256) void k_mlp1(const float* __restrict__ pooled, const float* __restrict__ W1,
                                              const float* __restrict__ b1, float* __restrict__ H1) {
    __shared__ float grow[256];
    int gi = blockIdx.x, t = threadIdx.x;
    grow[t] = pooled[(size_t)gi * 256 + t];
    __syncthreads();
    float acc = b1[t];
    #pragma unroll 8
    for (int k = 0; k < 256; ++k) acc = fmaf(grow[k], W1[k * 256 + t], acc);
    H1[gi * 256 + t] = fmaxf(acc, 0.f);
}

__global__ __launch_bounds__(128) void k_mlp2(const float* __restrict__ H1, const float* __restrict__ W2,
                                              const float* __restrict__ b2, float* __restrict__ H2) {
    __shared__ float row[256];
    int gi = blockIdx.x, t = threadIdx.x;
    row[t] = H1[gi * 256 + t];
    row[t + 128] = H1[gi * 256 + t + 128];
    __syncthreads();
    float acc = b2[t];
    #pragma unroll 8
    for (int k = 0; k < 256; ++k) acc = fmaf(row[k], W2[k * 128 + t], acc);
    H2[gi * 128 + t] = fmaxf(acc, 0.f);
}

__global__ __launch_bounds__(256) void k_mlp3(const float* __restrict__ H2, const float* __restrict__ W3,
                                              const float* __restrict__ b3, float* __restrict__ out) {
    int gi = blockIdx.x * 4 + (threadIdx.x >> 6);
    int lane = threadIdx.x & 63;
    float v = H2[gi * 128 + lane] * W3[lane] + H2[gi * 128 + 64 + lane] * W3[64 + lane];
    #pragma unroll
    for (int off = 32; off; off >>= 1) v += __shfl_down(v, off);
    if (lane == 0) out[gi] = v + b3[0];
}

extern "C" void kernel_launch(void* const* d_in, const int* in_sizes, int n_in,
                              void* d_out, int out_size, void* d_ws, size_t ws_size,
                              hipStream_t stream) {
    const float* x      = (const float*)d_in[0];
    const int*   ei     = (const int*)d_in[1];
    const int*   batch  = (const int*)d_in[2];
    const float* convW0 = (const float*)d_in[3];
    const float* convW  = (const float*)d_in[4];
    // d_in[5] convb: cancels inside BatchNorm, unused
    const float* gamma  = (const float*)d_in[6];
    const float* beta   = (const float*)d_in[7];
    const float* mW1    = (const float*)d_in[8];
    const float* mb1    = (const float*)d_in[9];
    const float* mW2    = (const float*)d_in[10];
    const float* mb2    = (const float*)d_in[11];
    const float* mW3    = (const float*)d_in[12];
    const float* mb3    = (const float*)d_in[13];
    float* out = (float*)d_out;

    const int E = in_sizes[1] / 2;
    const int n = in_sizes[0] / FH;
    const int npad = (n + 4) & ~3;
    const int nb = (n + 1023) / 1024;
    const int nbk = (n + 63) >> 6;            // 64-node buckets

    // workspace layout (16B-aligned chunks)
    float*          A     = (float*)d_ws;                     // n*128 f32 slot: bf16 H2; tmp overlays pre-loop
    unsigned short* H2b   = (unsigned short*)A;
    uint2*          tmp   = (uint2*)A;                        // E uint2 (6.4MB <= 25.6MB slot), pre-loop only
    float*    B       = A + (size_t)n * FH;                   // n*128 f32 slot: bf16 B; bcur overlays pre-loop
    unsigned short* Bb = (unsigned short*)B;
    int*      bcur    = (int*)B;                              // nbk*CPAD ints (50KB), pre-loop only
    float*    dinv    = B + (size_t)n * FH;                   // n
    unsigned* deg     = (unsigned*)(dinv + n);                // n
    float*    parts   = (float*)(deg + n);                    // NSB*256
    float*    sc      = parts + (size_t)NSB * 256;            // 128
    float*    sh      = sc + 128;                             // 128
    float*    pooled  = sh + 128;                             // G*256
    float*    h1      = pooled + (size_t)GG * 256;            // G*256
    float*    h2      = h1 + (size_t)GG * 256;                // G*128
    int*      gptr    = (int*)(h2 + (size_t)GG * FH);         // G+1 (pad 4)
    int*      rowptr  = gptr + ((GG + 4) & ~3);               // n+1 (padded)
    int*      bsum    = rowptr + npad;                        // 64
    int*      csrsrc  = bsum + 64;                            // E
    unsigned short* Wt = (unsigned short*)(csrsrc + ((E + 3) & ~3));  // 3*16384 ushorts

    const int* srcI = ei;
    const int* dstI = ei + E;

    // ---- CSR build (dense writes, low-contention atomics) + graph boundaries + W prep ----
    hipMemsetAsync(deg, 0, (size_t)n * sizeof(unsigned), stream);
    k_deg<<<(E + 255) / 256, 256, 0, stream>>>(dstI, deg, E);
    k_dinv<<<(n + 255) / 256, 256, 0, stream>>>(deg, dinv, n);
    k_scan1<<<nb, 1024, 0, stream>>>(deg, rowptr, bsum, n);
    k_scan2<<<1, 64, 0, stream>>>(bsum, rowptr + n, nb);
    k_scan3<<<nb, 1024, 0, stream>>>(rowptr, bsum, n);
    k_bcur<<<(nbk + 255) / 256, 256, 0, stream>>>(rowptr, bcur, nbk);
    k_binscatter<<<(E + EPB - 1) / EPB, 256, 0, stream>>>(srcI, dstI, bcur, tmp, E, nbk);
    k_finesort<<<nbk, 256, 0, stream>>>(tmp, rowptr, csrsrc, n);
    k_gptr<<<(GG + 1 + 255) / 256, 256, 0, stream>>>(batch, gptr, n);
    k_wprep<<<3 * 16384 / 256, 256, 0, stream>>>(convW0, convW, Wt);

    for (int l = 0; l < 3; ++l) {
        if (l == 0)
            k_gemm<false><<<(n + 63) / 64, 256, 0, stream>>>(x, Wt, dinv, nullptr, nullptr, H2b, n);
        else
            k_gemm<true><<<(n + 63) / 64, 256, 0, stream>>>(Bb, Wt + (size_t)l * 16384, dinv, sc, sh, H2b, n);
        k_aggregate<<<(n + 7) / 8, 256, 0, stream>>>(rowptr, csrsrc, dinv, H2b, Bb, n);
        k_stats<<<NSB, 256, 0, stream>>>(Bb, parts, n);
        k_finstats<<<1, 128, 0, stream>>>(parts, gamma + l * FH, beta + l * FH, sc, sh, n);
    }

    // pooling (applies layer-3 BN+ReLU on the fly), then MLP
    k_pool<<<GG, 256, 0, stream>>>(Bb, gptr, sc, sh, pooled);
    k_mlp1<<<GG, 256, 0, stream>>>(pooled, mW1, mb1, h1);
    k_mlp2<<<GG, 128, 0, stream>>>(h1, mW2, mb2, h2);
    k_mlp3<<<GG / 4, 256, 0, stream>>>(h2, mW3, mb3, out);
}